// Round 1
// 6842.056 us; speedup vs baseline: 1.0684x; 1.0684x over previous
//
#include <hip/hip_runtime.h>
#include <stdint.h>

#define BB 4
#define NN 4096
#define DD 64
#define BN (BB*NN)
#define STABF 1e-8f
#define NITER 100
// exp(-cost/eps) = exp2(cost * -1000*log2(e))
#define NEG_SCALE (-1442.695040888963f)

__device__ __forceinline__ float bf16lo(uint32_t w){ return __uint_as_float(w << 16); }
__device__ __forceinline__ float bf16hi(uint32_t w){ return __uint_as_float(w & 0xffff0000u); }
__device__ __forceinline__ uint32_t pack2bf(float f0, float f1){
  uint32_t u0 = __float_as_uint(f0); u0 += 0x7fffu + ((u0 >> 16) & 1u);
  uint32_t u1 = __float_as_uint(f1); u1 += 0x7fffu + ((u1 >> 16) & 1u);
  return (u0 >> 16) | (u1 & 0xffff0000u);
}
// LDS index swizzle: XOR column bits [0:2] with lane bits [2:4] (c bits 5..7).
// Bijective involution; turns the stride-8 ds_add pattern from a 16-way
// bank conflict into exact 2-way (free per m136).
__device__ __forceinline__ int swz(int c){ return c ^ ((c >> 5) & 7); }

// ---------------- init: acc slot0 = N (v0 = 1/(N+stab) ~ 1/N), slots 1,2 = 0
__global__ __launch_bounds__(256) void k_init(float* __restrict__ acc,
                                              float* __restrict__ partial) {
  int idx = blockIdx.x * 256 + threadIdx.x;   // grid = 64 blocks -> 16384 threads
  if (idx < BN) {
    acc[idx] = (float)NN;
    acc[BN + idx] = 0.f;
    acc[2 * BN + idx] = 0.f;
  }
  if (idx < 256) partial[idx] = 0.f;
}

// ---------------- softmax over last dim (64) for both x and y; also sum(p^2)
__global__ __launch_bounds__(256) void k_softmax(
    const float* __restrict__ x, const float* __restrict__ y,
    float* __restrict__ xf, float* __restrict__ yf,
    float* __restrict__ x2, float* __restrict__ y2) {
  int wave = (blockIdx.x * 256 + threadIdx.x) >> 6;   // grid 8192 -> 32768 waves
  int lane = threadIdx.x & 63;
  const float* src; float* dst; float* d2; int row;
  if (wave < BN) { src = x; dst = xf; d2 = x2; row = wave; }
  else           { src = y; dst = yf; d2 = y2; row = wave - BN; }
  float v = src[(size_t)row * DD + lane];
  float m = v;
  #pragma unroll
  for (int off = 32; off; off >>= 1) m = fmaxf(m, __shfl_xor(m, off));
  float e = __expf(v - m);
  float s = e;
  #pragma unroll
  for (int off = 32; off; off >>= 1) s += __shfl_xor(s, off);
  float p = e / s;
  dst[(size_t)row * DD + lane] = p;
  float q = p * p;
  #pragma unroll
  for (int off = 32; off; off >>= 1) q += __shfl_xor(q, off);
  if (lane == 0) d2[row] = q;
}

__device__ __forceinline__ void fma_row(float av0, float av1, const float4 bv,
                                        float cr0[4], float cr1[4]) {
  cr0[0] = fmaf(av0, bv.x, cr0[0]); cr0[1] = fmaf(av0, bv.y, cr0[1]);
  cr0[2] = fmaf(av0, bv.z, cr0[2]); cr0[3] = fmaf(av0, bv.w, cr0[3]);
  cr1[0] = fmaf(av1, bv.x, cr1[0]); cr1[1] = fmaf(av1, bv.y, cr1[1]);
  cr1[2] = fmaf(av1, bv.z, cr1[2]); cr1[3] = fmaf(av1, bv.w, cr1[3]);
}

// ---------------- build K (bf16): tile 32(i) x 64(j), thread micro-tile 2x4
__global__ __launch_bounds__(256) void k_build(
    const float* __restrict__ xf, const float* __restrict__ yf,
    const float* __restrict__ x2, const float* __restrict__ y2,
    unsigned short* __restrict__ K) {
  __shared__ float sxf[32][68];
  __shared__ float syt[64][68];   // transposed: syt[d][j]
  int bid = blockIdx.x, t = threadIdx.x;
  int jt = bid & 63, it = (bid >> 6) & 127, b = bid >> 13;
  int i0 = it * 32, j0 = jt * 64;
  {
    int r = t >> 3, c = (t & 7) * 8;
    const float* s0 = xf + ((size_t)(b*NN + i0 + r)) * DD + c;
    *(float4*)&sxf[r][c]     = *(const float4*)s0;
    *(float4*)&sxf[r][c + 4] = *(const float4*)(s0 + 4);
  }
  {
    int r = t >> 2, c0 = (t & 3) * 16;
    const float* s0 = yf + ((size_t)(b*NN + j0 + r)) * DD + c0;
    #pragma unroll
    for (int q = 0; q < 4; ++q) {
      float4 pv = *(const float4*)(s0 + q*4);
      syt[c0 + q*4 + 0][r] = pv.x;
      syt[c0 + q*4 + 1][r] = pv.y;
      syt[c0 + q*4 + 2][r] = pv.z;
      syt[c0 + q*4 + 3][r] = pv.w;
    }
  }
  __syncthreads();
  int tx = t & 15, ty = t >> 4;
  int ii = ty * 2, jj = tx * 4;
  float cr[2][4] = {{0,0,0,0},{0,0,0,0}};
  #pragma unroll
  for (int d = 0; d < DD; d += 4) {
    float4 a0 = *(const float4*)&sxf[ii][d];
    float4 a1 = *(const float4*)&sxf[ii + 1][d];
    float4 b0 = *(const float4*)&syt[d][jj];
    float4 b1 = *(const float4*)&syt[d + 1][jj];
    float4 b2 = *(const float4*)&syt[d + 2][jj];
    float4 b3 = *(const float4*)&syt[d + 3][jj];
    fma_row(a0.x, a1.x, b0, cr[0], cr[1]);
    fma_row(a0.y, a1.y, b1, cr[0], cr[1]);
    fma_row(a0.z, a1.z, b2, cr[0], cr[1]);
    fma_row(a0.w, a1.w, b3, cr[0], cr[1]);
  }
  float x2v[2], y2v[4];
  x2v[0] = x2[b*NN + i0 + ii]; x2v[1] = x2[b*NN + i0 + ii + 1];
  #pragma unroll
  for (int c = 0; c < 4; ++c) y2v[c] = y2[b*NN + j0 + jj + c];
  #pragma unroll
  for (int i2 = 0; i2 < 2; ++i2) {
    float k4[4];
    #pragma unroll
    for (int c = 0; c < 4; ++c) {
      float cost = fmaxf(x2v[i2] + y2v[c] - 2.f * cr[i2][c], 0.f);
      k4[c] = exp2f(cost * NEG_SCALE);
    }
    uint2 kw;
    kw.x = pack2bf(k4[0], k4[1]);
    kw.y = pack2bf(k4[2], k4[3]);
    *(uint2*)(K + ((size_t)(b*NN + i0 + ii + i2)) * NN + j0 + jj) = kw;
  }
}

// ---------------- FUSED iteration: one pass over K per Sinkhorn iteration.
// Each wave owns 8 rows (full 4096-col width, 64 cols/lane).
//   v regs   : 64/lane, rcp(accIn+stab), computed once
//   per row  : load 8 x uint4 (K row, held in regs), dot -> butterfly -> u_i,
//              then FMA same regs * u_i into 64 col-accumulators
//   epilogue : block-combine via swizzled LDS atomics, 4096 global atomics/block
// Triple-buffered acc: read rB, atomically accumulate into wB (pre-zeroed by
// the iteration before last), zero zB for the iteration after next.
__global__ __launch_bounds__(256, 2) void k_iter(
    const unsigned short* __restrict__ K,
    const float* __restrict__ accIn,
    float* __restrict__ accOut,
    float* __restrict__ accZ,
    float* __restrict__ u) {
  __shared__ float sacc[NN];
  int bid = blockIdx.x, t = threadIdx.x;     // grid = 512 = 4 batches * 128
  int wv = t >> 6, lane = t & 63;
  if (bid < 16) {
    *(float4*)(accZ + (size_t)(bid * 256 + t) * 4) = make_float4(0.f, 0.f, 0.f, 0.f);
  }
  #pragma unroll
  for (int q = 0; q < 16; ++q) sacc[q * 256 + t] = 0.f;

  int b = bid >> 7;
  int row0 = (bid & 127) * 32 + wv * 8;      // 32 rows/block, 8 rows/wave
  const float* ap = accIn + (size_t)b * NN + lane * 8;
  float vv[64];
  #pragma unroll
  for (int itn = 0; itn < 8; ++itn) {
    float4 a0 = *(const float4*)(ap + itn * 512);
    float4 a1 = *(const float4*)(ap + itn * 512 + 4);
    vv[itn*8+0] = __builtin_amdgcn_rcpf(a0.x + STABF);
    vv[itn*8+1] = __builtin_amdgcn_rcpf(a0.y + STABF);
    vv[itn*8+2] = __builtin_amdgcn_rcpf(a0.z + STABF);
    vv[itn*8+3] = __builtin_amdgcn_rcpf(a0.w + STABF);
    vv[itn*8+4] = __builtin_amdgcn_rcpf(a1.x + STABF);
    vv[itn*8+5] = __builtin_amdgcn_rcpf(a1.y + STABF);
    vv[itn*8+6] = __builtin_amdgcn_rcpf(a1.z + STABF);
    vv[itn*8+7] = __builtin_amdgcn_rcpf(a1.w + STABF);
  }
  float ca[64];
  #pragma unroll
  for (int q = 0; q < 64; ++q) ca[q] = 0.f;
  __syncthreads();   // LDS zeros visible before any ds_add below

  const unsigned short* Kbase = K + (size_t)(b * NN + row0) * NN + lane * 8;
  float* urow = u + b * NN + row0;
  #pragma unroll 1
  for (int r = 0; r < 8; ++r) {
    const unsigned short* Kp = Kbase + (size_t)r * NN;
    uint4 kw[8];
    #pragma unroll
    for (int itn = 0; itn < 8; ++itn) kw[itn] = *(const uint4*)(Kp + itn * 512);
    float sum = 0.f;
    #pragma unroll
    for (int itn = 0; itn < 8; ++itn) {
      sum = fmaf(bf16lo(kw[itn].x), vv[itn*8+0], sum);
      sum = fmaf(bf16hi(kw[itn].x), vv[itn*8+1], sum);
      sum = fmaf(bf16lo(kw[itn].y), vv[itn*8+2], sum);
      sum = fmaf(bf16hi(kw[itn].y), vv[itn*8+3], sum);
      sum = fmaf(bf16lo(kw[itn].z), vv[itn*8+4], sum);
      sum = fmaf(bf16hi(kw[itn].z), vv[itn*8+5], sum);
      sum = fmaf(bf16lo(kw[itn].w), vv[itn*8+6], sum);
      sum = fmaf(bf16hi(kw[itn].w), vv[itn*8+7], sum);
    }
    #pragma unroll
    for (int off = 32; off; off >>= 1) sum += __shfl_xor(sum, off);
    float ur = 1.0f / (sum + STABF);
    if (lane == 0) urow[r] = ur;
    #pragma unroll
    for (int itn = 0; itn < 8; ++itn) {
      ca[itn*8+0] = fmaf(bf16lo(kw[itn].x), ur, ca[itn*8+0]);
      ca[itn*8+1] = fmaf(bf16hi(kw[itn].x), ur, ca[itn*8+1]);
      ca[itn*8+2] = fmaf(bf16lo(kw[itn].y), ur, ca[itn*8+2]);
      ca[itn*8+3] = fmaf(bf16hi(kw[itn].y), ur, ca[itn*8+3]);
      ca[itn*8+4] = fmaf(bf16lo(kw[itn].z), ur, ca[itn*8+4]);
      ca[itn*8+5] = fmaf(bf16hi(kw[itn].z), ur, ca[itn*8+5]);
      ca[itn*8+6] = fmaf(bf16lo(kw[itn].w), ur, ca[itn*8+6]);
      ca[itn*8+7] = fmaf(bf16hi(kw[itn].w), ur, ca[itn*8+7]);
    }
  }
  int cbase = lane * 8;
  #pragma unroll
  for (int itn = 0; itn < 8; ++itn) {
    #pragma unroll
    for (int q = 0; q < 8; ++q)
      atomicAdd(&sacc[swz(itn * 512 + cbase + q)], ca[itn*8+q]);
  }
  __syncthreads();
  float* op = accOut + (size_t)b * NN;
  #pragma unroll
  for (int q = 0; q < 16; ++q) {
    int c = q * 256 + t;
    atomicAdd(op + c, sacc[swz(c)]);
  }
}

// ---------------- dist partials: sum u_i K_ij v_j cost_ij (cost recomputed)
__global__ __launch_bounds__(256) void k_final(
    const float* __restrict__ xf, const float* __restrict__ yf,
    const float* __restrict__ x2, const float* __restrict__ y2,
    const unsigned short* __restrict__ K, const float* __restrict__ u,
    const float* __restrict__ accv, float* __restrict__ partial) {
  __shared__ float sxf[32][68];
  __shared__ float syt[64][68];
  __shared__ float red[256];
  int bid = blockIdx.x, t = threadIdx.x;
  int jt = bid & 63, it = (bid >> 6) & 127, b = bid >> 13;
  int i0 = it * 32, j0 = jt * 64;
  {
    int r = t >> 3, c = (t & 7) * 8;
    const float* s0 = xf + ((size_t)(b*NN + i0 + r)) * DD + c;
    *(float4*)&sxf[r][c]     = *(const float4*)s0;
    *(float4*)&sxf[r][c + 4] = *(const float4*)(s0 + 4);
  }
  {
    int r = t >> 2, c0 = (t & 3) * 16;
    const float* s0 = yf + ((size_t)(b*NN + j0 + r)) * DD + c0;
    #pragma unroll
    for (int q = 0; q < 4; ++q) {
      float4 pv = *(const float4*)(s0 + q*4);
      syt[c0 + q*4 + 0][r] = pv.x;
      syt[c0 + q*4 + 1][r] = pv.y;
      syt[c0 + q*4 + 2][r] = pv.z;
      syt[c0 + q*4 + 3][r] = pv.w;
    }
  }
  __syncthreads();
  int tx = t & 15, ty = t >> 4;
  int ii = ty * 2, jj = tx * 4;
  float cr[2][4] = {{0,0,0,0},{0,0,0,0}};
  #pragma unroll
  for (int d = 0; d < DD; d += 4) {
    float4 a0 = *(const float4*)&sxf[ii][d];
    float4 a1 = *(const float4*)&sxf[ii + 1][d];
    float4 b0 = *(const float4*)&syt[d][jj];
    float4 b1 = *(const float4*)&syt[d + 1][jj];
    float4 b2 = *(const float4*)&syt[d + 2][jj];
    float4 b3 = *(const float4*)&syt[d + 3][jj];
    fma_row(a0.x, a1.x, b0, cr[0], cr[1]);
    fma_row(a0.y, a1.y, b1, cr[0], cr[1]);
    fma_row(a0.z, a1.z, b2, cr[0], cr[1]);
    fma_row(a0.w, a1.w, b3, cr[0], cr[1]);
  }
  float x2v[2], y2v[4], uv[2], vv[4];
  x2v[0] = x2[b*NN + i0 + ii]; x2v[1] = x2[b*NN + i0 + ii + 1];
  uv[0]  = u[b*NN + i0 + ii];  uv[1]  = u[b*NN + i0 + ii + 1];
  #pragma unroll
  for (int c = 0; c < 4; ++c) {
    y2v[c] = y2[b*NN + j0 + jj + c];
    vv[c]  = __builtin_amdgcn_rcpf(accv[b*NN + j0 + jj + c] + STABF);
  }
  float s = 0.f;
  #pragma unroll
  for (int i2 = 0; i2 < 2; ++i2) {
    uint2 kw = *(const uint2*)(K + ((size_t)(b*NN + i0 + ii + i2)) * NN + j0 + jj);
    float kk[4] = {bf16lo(kw.x), bf16hi(kw.x), bf16lo(kw.y), bf16hi(kw.y)};
    #pragma unroll
    for (int c = 0; c < 4; ++c) {
      float cost = fmaxf(x2v[i2] + y2v[c] - 2.f * cr[i2][c], 0.f);
      s = fmaf(uv[i2] * kk[c] * vv[c], cost, s);
    }
  }
  red[t] = s;
  __syncthreads();
  #pragma unroll
  for (int off = 128; off; off >>= 1) {
    if (t < off) red[t] += red[t + off];
    __syncthreads();
  }
  if (t == 0) atomicAdd(partial + (bid & 255), red[0]);
}

__global__ __launch_bounds__(256) void k_finalize(const float* __restrict__ partial,
                                                 float* __restrict__ out) {
  __shared__ float red[256];
  int t = threadIdx.x;
  red[t] = partial[t];
  __syncthreads();
  #pragma unroll
  for (int off = 128; off; off >>= 1) {
    if (t < off) red[t] += red[t + off];
    __syncthreads();
  }
  if (t == 0) out[0] = red[0];
}

extern "C" void kernel_launch(void* const* d_in, const int* in_sizes, int n_in,
                              void* d_out, int out_size, void* d_ws, size_t ws_size,
                              hipStream_t stream) {
  const float* x = (const float*)d_in[0];
  const float* y = (const float*)d_in[1];
  float* out = (float*)d_out;

  char* w = (char*)d_ws;
  unsigned short* K = (unsigned short*)w;                 // 134,217,728 B (bf16 [B,N,N])
  float* xf = (float*)(w + (size_t)BN * NN * 2);          // 4 MB
  float* yf = xf + (size_t)BN * DD;                       // 4 MB
  float* x2 = yf + (size_t)BN * DD;                       // 64 KB
  float* y2 = x2 + BN;                                    // 64 KB
  float* uu = y2 + BN;                                    // 64 KB
  float* acc = uu + BN;                                   // 3 x 64 KB (triple-buffered)
  float* partial = acc + 3 * BN;                          // 1 KB
  (void)in_sizes; (void)n_in; (void)out_size; (void)ws_size;

  k_init<<<64, 256, 0, stream>>>(acc, partial);
  k_softmax<<<8192, 256, 0, stream>>>(x, y, xf, yf, x2, y2);
  k_build<<<32768, 256, 0, stream>>>(xf, yf, x2, y2, K);

  // buffer rotation: iter t reads t%3, accumulates into (t+1)%3 (pre-zeroed),
  // zeroes (t+2)%3 (only referenced again as the write target of iter t+1).
  for (int itr = 0; itr < NITER; ++itr) {
    int rB = itr % 3, wB = (itr + 1) % 3, zB = (itr + 2) % 3;
    k_iter<<<512, 256, 0, stream>>>(K,
                                    acc + (size_t)rB * BN,
                                    acc + (size_t)wB * BN,
                                    acc + (size_t)zB * BN,
                                    uu);
  }
  // last iteration (itr=99) wrote acc slot (99+1)%3 = 1
  k_final<<<32768, 256, 0, stream>>>(xf, yf, x2, y2, K, uu, acc + BN, partial);
  k_finalize<<<1, 256, 0, stream>>>(partial, out);
}